// Round 5
// baseline (963.969 us; speedup 1.0000x reference)
//
#include <hip/hip_runtime.h>
#include <math.h>

#define TT 8
#define NTOK 12288
#define DD 256
#define NNODE 8192
#define NNODES 32768
#define CLEN 16
#define CDIM 64
#define CHUNK 2048
#define H1 128

__device__ __forceinline__ float gelu_exact(float v) {
    return 0.5f * v * (1.0f + erff(v * 0.70710678118654752f));
}

// ---- Kernel 0: G[c] = sum_k g[k]*w1[k,c]; B[c] = sum_k b[k]*w1[k,c] ----
__global__ __launch_bounds__(256) void k_prep(
    const float* __restrict__ ln1_g, const float* __restrict__ ln1_b,
    const float* __restrict__ w1, float* __restrict__ Gv, float* __restrict__ Bv)
{
    const int c = threadIdx.x & 127, h = threadIdx.x >> 7;
    __shared__ float gs[2][128], bs[2][128];
    float G = 0.f, B = 0.f;
    for (int k = h * 128; k < h * 128 + 128; ++k) {
        const float w = w1[(size_t)k * H1 + c];
        G += ln1_g[k] * w;
        B += ln1_b[k] * w;
    }
    gs[h][c] = G; bs[h][c] = B;
    __syncthreads();
    if (threadIdx.x < 128) {
        Gv[c] = gs[0][c] + gs[1][c];
        Bv[c] = bs[0][c] + bs[1][c];
    }
}

// ---- Kernel 1: x @ (g.*w1) with LN folded into epilogue; record rows per node ----
// grid (64 rowblocks, 8 t), block 256. Tile: 128 rows x 128 cols, BK=32, 8x8 microtile.
__global__ __launch_bounds__(256) void k_ln_gemm(
    const float* __restrict__ x, const int* __restrict__ indices,
    const float* __restrict__ ln1_g, const float* __restrict__ w1,
    const float* __restrict__ Gv, const float* __restrict__ Bv,
    float* __restrict__ y,
    int* __restrict__ cnt, int* __restrict__ slot0, int* __restrict__ slotsx,
    int* __restrict__ ovfcnt, int* __restrict__ ovf)
{
    const int t = blockIdx.y;
    const int rowBase = blockIdx.x * 128;
    const int tid = threadIdx.x;

    __shared__ float As[128 * 37];
    __shared__ float Bs[32 * 132];
    __shared__ float mS[128], rS[128];
    __shared__ float GS[128], BS[128];
    __shared__ float red[128][2][2];

    const float* xblk = x + ((size_t)t * NTOK + rowBase) * DD;

    if (tid < 128) {
        const int i = rowBase + tid;
        const int node = indices[t * NNODE + i];
        const int g = t * NNODES + node;
        const int pos = atomicAdd(&cnt[g], 1);
        if (pos == 0) slot0[g] = i;
        else if (pos <= 15) slotsx[(size_t)g * 15 + (pos - 1)] = i;
        else {
            const int op = atomicAdd(&ovfcnt[t], 1);
            ovf[t * NNODE + op] = (node << 13) | i;
        }
        GS[tid] = Gv[tid];
        BS[tid] = Bv[tid];
    }

    {
        const int row = tid >> 1, q = tid & 1;
        const float* xr = xblk + (size_t)row * DD + q * 4;
        float s = 0.f, ss = 0.f;
        #pragma unroll
        for (int u = 0; u < 32; ++u) {
            const float4 v = *(const float4*)(xr + u * 8);
            s  += v.x + v.y + v.z + v.w;
            ss += v.x*v.x + v.y*v.y + v.z*v.z + v.w*v.w;
        }
        red[row][q][0] = s;
        red[row][q][1] = ss;
    }
    __syncthreads();
    if (tid < 128) {
        const float s  = red[tid][0][0] + red[tid][1][0];
        const float ss = red[tid][0][1] + red[tid][1][1];
        const float m = s * (1.0f / 256.0f);
        const float var = ss * (1.0f / 256.0f) - m * m;
        mS[tid] = m;
        rS[tid] = rsqrtf(var + 1e-5f);
    }
    __syncthreads();

    const int ty = tid >> 4;
    const int tx = tid & 15;
    float acc[8][8];
    #pragma unroll
    for (int j = 0; j < 8; ++j)
        #pragma unroll
        for (int jj = 0; jj < 8; ++jj) acc[j][jj] = 0.f;

    for (int kt = 0; kt < 8; ++kt) {
        #pragma unroll
        for (int u = 0; u < 4; ++u) {
            const int f = tid + u * 256;
            const int row = f >> 3, c4 = f & 7;
            const float4 v = *(const float4*)(xblk + (size_t)row * DD + kt * 32 + c4 * 4);
            float* d = &As[37 * row + 4 * c4];
            d[0] = v.x; d[1] = v.y; d[2] = v.z; d[3] = v.w;
        }
        #pragma unroll
        for (int u = 0; u < 4; ++u) {
            const int f = tid + u * 256;
            const int k = f >> 5, c4 = f & 31;
            float4 v = *(const float4*)(w1 + (size_t)(kt * 32 + k) * H1 + c4 * 4);
            const float gk = ln1_g[kt * 32 + k];
            v.x *= gk; v.y *= gk; v.z *= gk; v.w *= gk;
            *(float4*)&Bs[132 * k + 4 * c4] = v;
        }
        __syncthreads();
        #pragma unroll
        for (int k = 0; k < 32; ++k) {
            float a[8];
            #pragma unroll
            for (int j = 0; j < 8; ++j) a[j] = As[37 * (8 * ty + j) + k];
            const float4 b0 = *(const float4*)&Bs[132 * k + 4 * tx];
            const float4 b1 = *(const float4*)&Bs[132 * k + 64 + 4 * tx];
            #pragma unroll
            for (int j = 0; j < 8; ++j) {
                acc[j][0] += a[j] * b0.x; acc[j][1] += a[j] * b0.y;
                acc[j][2] += a[j] * b0.z; acc[j][3] += a[j] * b0.w;
                acc[j][4] += a[j] * b1.x; acc[j][5] += a[j] * b1.y;
                acc[j][6] += a[j] * b1.z; acc[j][7] += a[j] * b1.w;
            }
        }
        __syncthreads();
    }

    const float4 g0 = *(const float4*)&GS[4 * tx];
    const float4 g1 = *(const float4*)&GS[64 + 4 * tx];
    const float4 bb0 = *(const float4*)&BS[4 * tx];
    const float4 bb1 = *(const float4*)&BS[64 + 4 * tx];
    #pragma unroll
    for (int j = 0; j < 8; ++j) {
        const int r = 8 * ty + j;
        const float m = mS[r], rr = rS[r];
        const float rm = rr * m;
        float* dst = y + (((size_t)t * NNODE + rowBase + r) << 7);
        float4 o0, o1;
        o0.x = rr * acc[j][0] - rm * g0.x + bb0.x;
        o0.y = rr * acc[j][1] - rm * g0.y + bb0.y;
        o0.z = rr * acc[j][2] - rm * g0.z + bb0.z;
        o0.w = rr * acc[j][3] - rm * g0.w + bb0.w;
        o1.x = rr * acc[j][4] - rm * g1.x + bb1.x;
        o1.y = rr * acc[j][5] - rm * g1.y + bb1.y;
        o1.z = rr * acc[j][6] - rm * g1.z + bb1.z;
        o1.w = rr * acc[j][7] - rm * g1.w + bb1.w;
        *(float4*)(dst + 4 * tx) = o0;
        *(float4*)(dst + 64 + 4 * tx) = o1;
    }
}

// ---- Kernel 1b: classify nodes & rows. grid (128, 8), block 256 ----
// node part: zero-count nodes -> zc[t][l]; multi nodes -> mlist.
// row part: rowl[t][i] = chunk l if row's node is singleton else -1.
__global__ __launch_bounds__(256) void k_classify(
    const int* __restrict__ indices, const int* __restrict__ cnt,
    int* __restrict__ rowl, int* __restrict__ mlist, int* __restrict__ mcnt,
    int* __restrict__ zc)
{
    const int t = blockIdx.y;
    const int nid = blockIdx.x * 256 + threadIdx.x;
    const int n = cnt[t * NNODES + nid];
    if (n == 0) atomicAdd(&zc[t * CLEN + (nid >> 11)], 1);
    else if (n >= 2) {
        const int p = atomicAdd(&mcnt[t], 1);
        mlist[t * NNODE + p] = nid;
    }
    if (nid < NNODE) {
        const int node = indices[t * NNODE + nid];
        rowl[t * NNODE + nid] = (cnt[t * NNODES + node] == 1) ? (node >> 11) : -1;
    }
}

// ---- Kernel 2a: singleton rows, streaming. grid (64, 8), block 256 ----
__global__ __launch_bounds__(256) void k_rowsum(
    const float* __restrict__ y, const float* __restrict__ b1,
    const int* __restrict__ rowl, float* __restrict__ sbuf)
{
    const int tid = threadIdx.x;
    const int rb = blockIdx.x * 128;
    const int t = blockIdx.y;
    __shared__ float accS[2][CLEN][H1];   // 16 KiB, thread-private columns
    __shared__ int rl[128];
    for (int e = tid; e < 2 * CLEN * H1; e += 256) ((float*)accS)[e] = 0.f;
    if (tid < 128) rl[tid] = rowl[t * NNODE + rb + tid];
    __syncthreads();
    const int c = tid & 127, h = tid >> 7;
    const float b1c = b1[c];
    const float* ybase = y + (((size_t)t * NNODE + rb) << 7) + c;
    #pragma unroll 4
    for (int r = h; r < 128; r += 2) {
        const float v = ybase[(size_t)r << 7];   // address independent of data
        const int l = rl[r];                      // wave-uniform
        if (l >= 0) accS[h][l][c] += gelu_exact(v + b1c);
    }
    __syncthreads();
    for (int e = tid; e < CLEN * H1; e += 256) {
        const int l = e >> 7, cc = e & 127;
        const float s = accS[0][l][cc] + accS[1][l][cc];
        if (s != 0.f) atomicAdd(&sbuf[(t * CLEN + l) * H1 + cc], s);
    }
}

// ---- Kernel 2b: multi-count nodes. grid (16, 8), block 256 ----
__global__ __launch_bounds__(256) void k_multi(
    const float* __restrict__ y, const float* __restrict__ b1,
    const int* __restrict__ cnt, const int* __restrict__ slot0,
    const int* __restrict__ slotsx,
    const int* __restrict__ ovfcnt, const int* __restrict__ ovf,
    const int* __restrict__ mlist, const int* __restrict__ mcnt,
    float* __restrict__ sbuf)
{
    const int tid = threadIdx.x;
    const int t = blockIdx.y;
    __shared__ float accS[2][CLEN][H1];
    for (int e = tid; e < 2 * CLEN * H1; e += 256) ((float*)accS)[e] = 0.f;
    __syncthreads();
    const int c = tid & 127, h = tid >> 7;
    const float b1c = b1[c];
    const float* ybase = y + (((size_t)t * NNODE) << 7) + c;
    int mn = mcnt[t]; if (mn > NNODE) mn = NNODE;
    for (int j = blockIdx.x * 2 + h; j < mn; j += 32) {
        const int node = mlist[t * NNODE + j];      // wave-uniform
        const int g = t * NNODES + node;
        const int n = cnt[g];
        float acc = b1c + ybase[(size_t)slot0[g] << 7];
        const int m = n < 16 ? n : 16;
        const int* sx = slotsx + (size_t)g * 15;
        for (int q = 0; q < m - 1; ++q)
            acc += ybase[(size_t)sx[q] << 7];
        if (n > 16) {
            int oc = ovfcnt[t]; if (oc > NNODE) oc = NNODE;
            for (int e = 0; e < oc; ++e) {
                const int v = ovf[t * NNODE + e];
                if ((v >> 13) == node) acc += ybase[(size_t)(v & 8191) << 7];
            }
        }
        accS[h][node >> 11][c] += gelu_exact(acc);
    }
    __syncthreads();
    for (int e = tid; e < CLEN * H1; e += 256) {
        const int l = e >> 7, cc = e & 127;
        const float s = accS[0][l][cc] + accS[1][l][cc];
        if (s != 0.f) atomicAdd(&sbuf[(t * CLEN + l) * H1 + cc], s);
    }
}

// ---- Kernel 3: decode. grid 8, block 1024. ----
__global__ __launch_bounds__(1024) void k_decode(
    const float* __restrict__ sbuf, const int* __restrict__ zc,
    const float* __restrict__ b1,
    const float* __restrict__ w2, const float* __restrict__ b2,
    const float* __restrict__ lnf_g, const float* __restrict__ lnf_b,
    const float* __restrict__ lnd_g, const float* __restrict__ lnd_b,
    const float* __restrict__ dw1, const float* __restrict__ db1,
    const float* __restrict__ dw2, const float* __restrict__ db2,
    float* __restrict__ decRow)
{
    const int t = blockIdx.x, tid = threadIdx.x;
    __shared__ float wbuf[16384];      // 64 KiB staging
    __shared__ float sb[CLEN * H1];    // 8 KiB
    __shared__ float comp[1024];
    __shared__ float vv[1024];
    __shared__ float hh[CLEN * H1];
    __shared__ float redA[16], redB[16];
    __shared__ float mvS[2];

    // stage sb (+ zero-node analytic term) and w2
    for (int e = tid; e < CLEN * H1; e += 1024) {
        const int l = e >> 7, k = e & 127;
        sb[e] = sbuf[t * CLEN * H1 + e] + (float)zc[t * CLEN + l] * gelu_exact(b1[k]);
    }
    #pragma unroll
    for (int u = 0; u < 2; ++u) {
        const int j4 = (tid + u * 1024) * 4;
        *(float4*)&wbuf[j4] = *(const float4*)(w2 + j4);
    }
    __syncthreads();

    // 1) comp = sb @ w2 + CHUNK*b2  (1024 outputs, 1 per thread)
    {
        const int l = tid >> 6, cc = tid & 63;
        const float* sp = sb + l * H1;
        float a0 = 0.f, a1 = 0.f, a2 = 0.f, a3 = 0.f;
        for (int k = 0; k < H1; k += 4) {
            a0 += sp[k + 0] * wbuf[(k + 0) * CDIM + cc];
            a1 += sp[k + 1] * wbuf[(k + 1) * CDIM + cc];
            a2 += sp[k + 2] * wbuf[(k + 2) * CDIM + cc];
            a3 += sp[k + 3] * wbuf[(k + 3) * CDIM + cc];
        }
        comp[tid] = (float)CHUNK * b2[cc] + ((a0 + a1) + (a2 + a3));
    }
    __syncthreads();

    // 2) lnf over 1024 (wave shuffle + tiny serial)
    {
        float v = comp[tid];
        float s = v, ss = v * v;
        #pragma unroll
        for (int off = 32; off >= 1; off >>= 1) {
            s  += __shfl_xor(s, off, 64);
            ss += __shfl_xor(ss, off, 64);
        }
        if ((tid & 63) == 0) { redA[tid >> 6] = s; redB[tid >> 6] = ss; }
        __syncthreads();
        if (tid == 0) {
            float sa = 0.f, sb2 = 0.f;
            for (int w = 0; w < 16; ++w) { sa += redA[w]; sb2 += redB[w]; }
            const float m = sa * (1.0f / 1024.0f);
            const float var = sb2 * (1.0f / 1024.0f) - m * m;
            mvS[0] = m; mvS[1] = rsqrtf(var + 1e-5f);
        }
        __syncthreads();
        const float m = mvS[0], r = mvS[1];
        comp[tid] = (v - m) * r * lnf_g[tid] + lnf_b[tid];
    }
    __syncthreads();

    // 3) lnd: one wave per l (16 waves, 64 lanes = 64 cols)
    {
        const int cc = tid & 63;
        const float v = comp[tid];
        float s = v, ss = v * v;
        #pragma unroll
        for (int off = 32; off >= 1; off >>= 1) {
            s  += __shfl_xor(s, off, 64);
            ss += __shfl_xor(ss, off, 64);
        }
        const float m = s * (1.0f / 64.0f);
        const float var = ss * (1.0f / 64.0f) - m * m;
        const float r = rsqrtf(var + 1e-5f);
        vv[tid] = (v - m) * r * lnd_g[cc] + lnd_b[cc];
    }
    __syncthreads();

    // 4) hh = gelu(vv @ dw1 + db1): stage dw1 (64x128), 2048 outputs
    #pragma unroll
    for (int u = 0; u < 2; ++u) {
        const int j4 = (tid + u * 1024) * 4;
        *(float4*)&wbuf[j4] = *(const float4*)(dw1 + j4);
    }
    __syncthreads();
    #pragma unroll
    for (int u = 0; u < 2; ++u) {
        const int j = tid + u * 1024;
        const int l = j >> 7, cc = j & 127;
        const float* vp = vv + l * CDIM;
        float a0 = 0.f, a1 = 0.f, a2 = 0.f, a3 = 0.f;
        for (int k = 0; k < CDIM; k += 4) {
            a0 += vp[k + 0] * wbuf[(k + 0) * H1 + cc];
            a1 += vp[k + 1] * wbuf[(k + 1) * H1 + cc];
            a2 += vp[k + 2] * wbuf[(k + 2) * H1 + cc];
            a3 += vp[k + 3] * wbuf[(k + 3) * H1 + cc];
        }
        hh[j] = gelu_exact(db1[cc] + ((a0 + a1) + (a2 + a3)));
    }
    __syncthreads();

    // 5) decRow = hh @ dw2 + db2, dw2 staged in two 128-col halves
    for (int half = 0; half < 2; ++half) {
        #pragma unroll
        for (int u = 0; u < 4; ++u) {
            const int e = tid + u * 1024;       // 0..4095 float4s
            const int row = e >> 5, cq = e & 31;
            *(float4*)&wbuf[row * 128 + cq * 4] =
                *(const float4*)(dw2 + (size_t)row * DD + half * 128 + cq * 4);
        }
        __syncthreads();
        #pragma unroll
        for (int u = 0; u < 2; ++u) {
            const int j = tid + u * 1024;       // 0..2047
            const int l = j >> 7, cc = j & 127;
            const float* hp = hh + l * H1;
            float a0 = 0.f, a1 = 0.f, a2 = 0.f, a3 = 0.f;
            for (int k = 0; k < H1; k += 4) {
                a0 += hp[k + 0] * wbuf[(k + 0) * 128 + cc];
                a1 += hp[k + 1] * wbuf[(k + 1) * 128 + cc];
                a2 += hp[k + 2] * wbuf[(k + 2) * 128 + cc];
                a3 += hp[k + 3] * wbuf[(k + 3) * 128 + cc];
            }
            decRow[(t * CLEN + l) * DD + half * 128 + cc] =
                db2[half * 128 + cc] + ((a0 + a1) + (a2 + a3));
        }
        __syncthreads();
    }
}

// ---- Kernel 4: out[t,i,:] = decRow[t, idx[t,i]>>11, :] for i<8192 else 0 ----
__global__ __launch_bounds__(256) void k_gather(
    const int* __restrict__ indices, const float* __restrict__ decRow,
    float* __restrict__ out)
{
    const int tid = threadIdx.x;
    const int r = blockIdx.x * 4 + (tid >> 6);
    const int c4 = tid & 63;
    const int t = r / NTOK;
    const int i = r - t * NTOK;
    float4 v = make_float4(0.f, 0.f, 0.f, 0.f);
    if (i < NNODE) {
        const int node = indices[t * NNODE + i];
        const int l = node >> 11;
        v = *(const float4*)(decRow + (t * CLEN + l) * DD + c4 * 4);
    }
    *(float4*)(out + (size_t)r * DD + c4 * 4) = v;
}

extern "C" void kernel_launch(void* const* d_in, const int* in_sizes, int n_in,
                              void* d_out, int out_size, void* d_ws, size_t ws_size,
                              hipStream_t stream)
{
    const float* x       = (const float*)d_in[0];
    const int*   indices = (const int*)d_in[1];
    const float* ln1_g   = (const float*)d_in[2];
    const float* ln1_b   = (const float*)d_in[3];
    const float* w1      = (const float*)d_in[4];
    const float* b1      = (const float*)d_in[5];
    const float* w2      = (const float*)d_in[6];
    const float* b2      = (const float*)d_in[7];
    const float* lnf_g   = (const float*)d_in[8];
    const float* lnf_b   = (const float*)d_in[9];
    const float* lnd_g   = (const float*)d_in[10];
    const float* lnd_b   = (const float*)d_in[11];
    const float* dw1     = (const float*)d_in[12];
    const float* db1     = (const float*)d_in[13];
    const float* dw2     = (const float*)d_in[14];
    const float* db2     = (const float*)d_in[15];
    float* out = (float*)d_out;

    char* ws = (char*)d_ws;
    // zeroed region [0, 0x110240): cnt, ovfcnt, zc, mcnt, sbuf
    int*   cnt    = (int*)ws;                            // 1 MiB
    int*   ovfcnt = (int*)(ws + 0x100000);               // 32 B
    int*   zc     = (int*)(ws + 0x100020);               // 512 B
    int*   mcnt   = (int*)(ws + 0x100220);               // 32 B
    float* sbuf   = (float*)(ws + 0x100240);             // 64 KiB
    int*   slot0  = (int*)(ws + 0x120000);               // 1 MiB
    int*   slotsx = (int*)(ws + 0x220000);               // 15 MiB -> 0x1120000
    int*   ovf    = (int*)(ws + 0x1120000);              // 256 KiB
    float* decRow = (float*)(ws + 0x1160000);            // 128 KiB
    float* Gv     = (float*)(ws + 0x1180000);            // 512 B
    float* Bv     = (float*)(ws + 0x1180200);            // 512 B
    int*   rowl   = (int*)(ws + 0x1180400);              // 256 KiB
    int*   mlist  = (int*)(ws + 0x11C0400);              // 256 KiB
    float* y      = (float*)(ws + 0x1300000);            // 32 MiB

    hipMemsetAsync(ws, 0, 0x110240, stream);

    k_prep<<<1, 256, 0, stream>>>(ln1_g, ln1_b, w1, Gv, Bv);
    k_ln_gemm<<<dim3(64, 8), 256, 0, stream>>>(x, indices, ln1_g, w1, Gv, Bv, y,
                                               cnt, slot0, slotsx, ovfcnt, ovf);
    k_classify<<<dim3(128, 8), 256, 0, stream>>>(indices, cnt, rowl, mlist, mcnt, zc);
    k_rowsum<<<dim3(64, 8), 256, 0, stream>>>(y, b1, rowl, sbuf);
    k_multi<<<dim3(16, 8), 256, 0, stream>>>(y, b1, cnt, slot0, slotsx,
                                             ovfcnt, ovf, mlist, mcnt, sbuf);
    k_decode<<<8, 1024, 0, stream>>>(sbuf, zc, b1, w2, b2, lnf_g, lnf_b,
                                     lnd_g, lnd_b, dw1, db1, dw2, db2, decRow);
    k_gather<<<24576, 256, 0, stream>>>(indices, decRow, out);
}

// Round 6
// 396.859 us; speedup vs baseline: 2.4290x; 2.4290x over previous
//
#include <hip/hip_runtime.h>
#include <math.h>

#define TT 8
#define NTOK 12288
#define DD 256
#define NNODE 8192
#define NNODES 32768
#define CLEN 16
#define CDIM 64
#define CHUNK 2048
#define H1 128

__device__ __forceinline__ float gelu_exact(float v) {
    return 0.5f * v * (1.0f + erff(v * 0.70710678118654752f));
}

// ---- Kernel 0: G[c] = sum_k g[k]*w1[k,c]; B[c] = sum_k b[k]*w1[k,c] ----
__global__ __launch_bounds__(256) void k_prep(
    const float* __restrict__ ln1_g, const float* __restrict__ ln1_b,
    const float* __restrict__ w1, float* __restrict__ Gv, float* __restrict__ Bv)
{
    const int c = threadIdx.x & 127, h = threadIdx.x >> 7;
    __shared__ float gs[2][128], bs[2][128];
    float G = 0.f, B = 0.f;
    for (int k = h * 128; k < h * 128 + 128; ++k) {
        const float w = w1[(size_t)k * H1 + c];
        G += ln1_g[k] * w;
        B += ln1_b[k] * w;
    }
    gs[h][c] = G; bs[h][c] = B;
    __syncthreads();
    if (threadIdx.x < 128) {
        Gv[c] = gs[0][c] + gs[1][c];
        Bv[c] = bs[0][c] + bs[1][c];
    }
}

// ---- Kernel 1: x @ (g.*w1) with LN folded into epilogue; record rows per node ----
// grid (64 rowblocks, 8 t), block 256. Tile: 128 rows x 128 cols, BK=32, 8x8 microtile.
__global__ __launch_bounds__(256) void k_ln_gemm(
    const float* __restrict__ x, const int* __restrict__ indices,
    const float* __restrict__ ln1_g, const float* __restrict__ w1,
    const float* __restrict__ Gv, const float* __restrict__ Bv,
    float* __restrict__ y,
    int* __restrict__ cnt, int* __restrict__ slot0, int* __restrict__ slotsx,
    int* __restrict__ ovfcnt, int* __restrict__ ovf)
{
    const int t = blockIdx.y;
    const int rowBase = blockIdx.x * 128;
    const int tid = threadIdx.x;

    __shared__ float As[128 * 37];
    __shared__ float Bs[32 * 132];
    __shared__ float mS[128], rS[128];
    __shared__ float GS[128], BS[128];
    __shared__ float red[128][2][2];

    const float* xblk = x + ((size_t)t * NTOK + rowBase) * DD;

    if (tid < 128) {
        const int i = rowBase + tid;
        const int node = indices[t * NNODE + i];
        const int g = t * NNODES + node;
        const int pos = atomicAdd(&cnt[g], 1);
        if (pos == 0) slot0[g] = i;
        else if (pos <= 15) slotsx[(size_t)g * 15 + (pos - 1)] = i;
        else {
            const int op = atomicAdd(&ovfcnt[t], 1);
            ovf[t * NNODE + op] = (node << 13) | i;
        }
        GS[tid] = Gv[tid];
        BS[tid] = Bv[tid];
    }

    {
        const int row = tid >> 1, q = tid & 1;
        const float* xr = xblk + (size_t)row * DD + q * 4;
        float s = 0.f, ss = 0.f;
        #pragma unroll
        for (int u = 0; u < 32; ++u) {
            const float4 v = *(const float4*)(xr + u * 8);
            s  += v.x + v.y + v.z + v.w;
            ss += v.x*v.x + v.y*v.y + v.z*v.z + v.w*v.w;
        }
        red[row][q][0] = s;
        red[row][q][1] = ss;
    }
    __syncthreads();
    if (tid < 128) {
        const float s  = red[tid][0][0] + red[tid][1][0];
        const float ss = red[tid][0][1] + red[tid][1][1];
        const float m = s * (1.0f / 256.0f);
        const float var = ss * (1.0f / 256.0f) - m * m;
        mS[tid] = m;
        rS[tid] = rsqrtf(var + 1e-5f);
    }
    __syncthreads();

    const int ty = tid >> 4;
    const int tx = tid & 15;
    float acc[8][8];
    #pragma unroll
    for (int j = 0; j < 8; ++j)
        #pragma unroll
        for (int jj = 0; jj < 8; ++jj) acc[j][jj] = 0.f;

    for (int kt = 0; kt < 8; ++kt) {
        #pragma unroll
        for (int u = 0; u < 4; ++u) {
            const int f = tid + u * 256;
            const int row = f >> 3, c4 = f & 7;
            const float4 v = *(const float4*)(xblk + (size_t)row * DD + kt * 32 + c4 * 4);
            float* d = &As[37 * row + 4 * c4];
            d[0] = v.x; d[1] = v.y; d[2] = v.z; d[3] = v.w;
        }
        #pragma unroll
        for (int u = 0; u < 4; ++u) {
            const int f = tid + u * 256;
            const int k = f >> 5, c4 = f & 31;
            float4 v = *(const float4*)(w1 + (size_t)(kt * 32 + k) * H1 + c4 * 4);
            const float gk = ln1_g[kt * 32 + k];
            v.x *= gk; v.y *= gk; v.z *= gk; v.w *= gk;
            *(float4*)&Bs[132 * k + 4 * c4] = v;
        }
        __syncthreads();
        #pragma unroll
        for (int k = 0; k < 32; ++k) {
            float a[8];
            #pragma unroll
            for (int j = 0; j < 8; ++j) a[j] = As[37 * (8 * ty + j) + k];
            const float4 b0 = *(const float4*)&Bs[132 * k + 4 * tx];
            const float4 b1 = *(const float4*)&Bs[132 * k + 64 + 4 * tx];
            #pragma unroll
            for (int j = 0; j < 8; ++j) {
                acc[j][0] += a[j] * b0.x; acc[j][1] += a[j] * b0.y;
                acc[j][2] += a[j] * b0.z; acc[j][3] += a[j] * b0.w;
                acc[j][4] += a[j] * b1.x; acc[j][5] += a[j] * b1.y;
                acc[j][6] += a[j] * b1.z; acc[j][7] += a[j] * b1.w;
            }
        }
        __syncthreads();
    }

    const float4 g0 = *(const float4*)&GS[4 * tx];
    const float4 g1 = *(const float4*)&GS[64 + 4 * tx];
    const float4 bb0 = *(const float4*)&BS[4 * tx];
    const float4 bb1 = *(const float4*)&BS[64 + 4 * tx];
    #pragma unroll
    for (int j = 0; j < 8; ++j) {
        const int r = 8 * ty + j;
        const float m = mS[r], rr = rS[r];
        const float rm = rr * m;
        float* dst = y + (((size_t)t * NNODE + rowBase + r) << 7);
        float4 o0, o1;
        o0.x = rr * acc[j][0] - rm * g0.x + bb0.x;
        o0.y = rr * acc[j][1] - rm * g0.y + bb0.y;
        o0.z = rr * acc[j][2] - rm * g0.z + bb0.z;
        o0.w = rr * acc[j][3] - rm * g0.w + bb0.w;
        o1.x = rr * acc[j][4] - rm * g1.x + bb1.x;
        o1.y = rr * acc[j][5] - rm * g1.y + bb1.y;
        o1.z = rr * acc[j][6] - rm * g1.z + bb1.z;
        o1.w = rr * acc[j][7] - rm * g1.w + bb1.w;
        *(float4*)(dst + 4 * tx) = o0;
        *(float4*)(dst + 64 + 4 * tx) = o1;
    }
}

// ---- Kernel 1b: classify. grid (l 16, t 8), block 256 — one block per chunk. ----
// NO global atomics: LDS count/list, plain stores.
__global__ __launch_bounds__(256) void k_classify(
    const int* __restrict__ indices, const int* __restrict__ cnt,
    int* __restrict__ rowl, int* __restrict__ mlist, int* __restrict__ mcntc,
    int* __restrict__ zc)
{
    const int l = blockIdx.x, t = blockIdx.y, tid = threadIdx.x;
    __shared__ int mcount;
    __shared__ int mlocal[2048];
    __shared__ int zred[256];
    if (tid == 0) mcount = 0;
    __syncthreads();
    int z = 0;
    #pragma unroll
    for (int u = 0; u < 8; ++u) {
        const int nid = l * 2048 + u * 256 + tid;
        const int n = cnt[t * NNODES + nid];
        if (n == 0) ++z;
        else if (n >= 2) mlocal[atomicAdd(&mcount, 1)] = nid;   // LDS atomic
    }
    zred[tid] = z;
    __syncthreads();
    for (int st = 128; st > 0; st >>= 1) {
        if (tid < st) zred[tid] += zred[tid + st];
        __syncthreads();
    }
    const int mc = mcount;
    if (tid == 0) { zc[t * CLEN + l] = zred[0]; mcntc[t * CLEN + l] = mc; }
    for (int j = tid; j < mc; j += 256)
        mlist[(t * CLEN + l) * 2048 + j] = mlocal[j];
    // rowl for rows [l*512, l*512+512)
    #pragma unroll
    for (int u = 0; u < 2; ++u) {
        const int i = l * 512 + u * 256 + tid;
        const int node = indices[t * NNODE + i];
        rowl[t * NNODE + i] = (cnt[t * NNODES + node] == 1) ? (node >> 11) : -1;
    }
}

// ---- Kernel 2a: singleton rows, streaming -> partial sums. grid (64, 8), block 256 ----
__global__ __launch_bounds__(256) void k_rowsum(
    const float* __restrict__ y, const float* __restrict__ b1,
    const int* __restrict__ rowl, float* __restrict__ pbuf)
{
    const int tid = threadIdx.x;
    const int rb = blockIdx.x * 128;
    const int t = blockIdx.y;
    __shared__ float accS[2][CLEN][H1];   // 16 KiB
    __shared__ int rl[128];
    for (int e = tid; e < 2 * CLEN * H1; e += 256) ((float*)accS)[e] = 0.f;
    if (tid < 128) rl[tid] = rowl[t * NNODE + rb + tid];
    __syncthreads();
    const int c = tid & 127, h = tid >> 7;
    const float b1c = b1[c];
    const float* ybase = y + (((size_t)t * NNODE + rb) << 7) + c;
    #pragma unroll 4
    for (int r = h; r < 128; r += 2) {
        const float v = ybase[(size_t)r << 7];
        const int l = rl[r];               // wave-uniform
        if (l >= 0) accS[h][l][c] += gelu_exact(v + b1c);
    }
    __syncthreads();
    float* pb = pbuf + ((size_t)t * 64 + blockIdx.x) * (CLEN * H1);
    for (int e = tid; e < CLEN * H1; e += 256) {
        const int l = e >> 7, cc = e & 127;
        pb[e] = accS[0][l][cc] + accS[1][l][cc];   // plain store
    }
}

// ---- Kernel 2b: multi-count nodes -> partial sums. grid (sub 4, l 16, t 8), block 256 ----
__global__ __launch_bounds__(256) void k_multi(
    const float* __restrict__ y, const float* __restrict__ b1,
    const int* __restrict__ cnt, const int* __restrict__ slot0,
    const int* __restrict__ slotsx,
    const int* __restrict__ ovfcnt, const int* __restrict__ ovf,
    const int* __restrict__ mlist, const int* __restrict__ mcntc,
    float* __restrict__ pbuf2)
{
    const int sub = blockIdx.x, l = blockIdx.y, t = blockIdx.z;
    const int tid = threadIdx.x;
    const int c = tid & 127, h = tid >> 7;
    __shared__ float accS2[2][128];
    const float b1c = b1[c];
    const float* ybase = y + (((size_t)t * NNODE) << 7) + c;
    const int mc = mcntc[t * CLEN + l];
    const int* ml = mlist + (t * CLEN + l) * 2048;
    float cs = 0.f;
    for (int j = sub * 2 + h; j < mc; j += 8) {
        const int node = ml[j];            // wave-uniform
        const int g = t * NNODES + node;
        const int n = cnt[g];
        float acc = b1c + ybase[(size_t)slot0[g] << 7];
        const int m = n < 16 ? n : 16;
        const int* sx = slotsx + (size_t)g * 15;
        for (int q = 0; q < m - 1; ++q)
            acc += ybase[(size_t)sx[q] << 7];
        if (n > 16) {
            int oc = ovfcnt[t]; if (oc > NNODE) oc = NNODE;
            for (int e = 0; e < oc; ++e) {
                const int v = ovf[t * NNODE + e];
                if ((v >> 13) == node) acc += ybase[(size_t)(v & 8191) << 7];
            }
        }
        cs += gelu_exact(acc);
    }
    accS2[h][c] = cs;
    __syncthreads();
    if (tid < 128)
        pbuf2[((t * CLEN + l) * 4 + sub) * 128 + c] = accS2[0][c] + accS2[1][c];
}

// ---- Kernel 2c: sbuf = sum of partials. grid (8 t), block 1024 ----
__global__ __launch_bounds__(1024) void k_sreduce(
    const float* __restrict__ pbuf, const float* __restrict__ pbuf2,
    float* __restrict__ sbuf)
{
    const int t = blockIdx.x, tid = threadIdx.x;
    #pragma unroll
    for (int u = 0; u < 2; ++u) {
        const int e = tid + u * 1024;
        float s = 0.f;
        const float* pp = pbuf + (size_t)t * 64 * (CLEN * H1) + e;
        #pragma unroll 8
        for (int p = 0; p < 64; ++p) s += pp[(size_t)p * (CLEN * H1)];
        const int l = e >> 7, cc = e & 127;
        const float* q = pbuf2 + ((t * CLEN + l) * 4) * 128 + cc;
        s += (q[0] + q[128]) + (q[256] + q[384]);
        sbuf[t * (CLEN * H1) + e] = s;
    }
}

// ---- Kernel 3: decode. grid 8, block 1024. ----
__global__ __launch_bounds__(1024) void k_decode(
    const float* __restrict__ sbuf, const int* __restrict__ zc,
    const float* __restrict__ b1,
    const float* __restrict__ w2, const float* __restrict__ b2,
    const float* __restrict__ lnf_g, const float* __restrict__ lnf_b,
    const float* __restrict__ lnd_g, const float* __restrict__ lnd_b,
    const float* __restrict__ dw1, const float* __restrict__ db1,
    const float* __restrict__ dw2, const float* __restrict__ db2,
    float* __restrict__ decRow)
{
    const int t = blockIdx.x, tid = threadIdx.x;
    __shared__ float wbuf[16384];
    __shared__ float sb[CLEN * H1];
    __shared__ float comp[1024];
    __shared__ float vv[1024];
    __shared__ float hh[CLEN * H1];
    __shared__ float redA[16], redB[16];
    __shared__ float mvS[2];

    for (int e = tid; e < CLEN * H1; e += 1024) {
        const int l = e >> 7, k = e & 127;
        sb[e] = sbuf[t * CLEN * H1 + e] + (float)zc[t * CLEN + l] * gelu_exact(b1[k]);
    }
    #pragma unroll
    for (int u = 0; u < 2; ++u) {
        const int j4 = (tid + u * 1024) * 4;
        *(float4*)&wbuf[j4] = *(const float4*)(w2 + j4);
    }
    __syncthreads();

    {
        const int l = tid >> 6, cc = tid & 63;
        const float* sp = sb + l * H1;
        float a0 = 0.f, a1 = 0.f, a2 = 0.f, a3 = 0.f;
        for (int k = 0; k < H1; k += 4) {
            a0 += sp[k + 0] * wbuf[(k + 0) * CDIM + cc];
            a1 += sp[k + 1] * wbuf[(k + 1) * CDIM + cc];
            a2 += sp[k + 2] * wbuf[(k + 2) * CDIM + cc];
            a3 += sp[k + 3] * wbuf[(k + 3) * CDIM + cc];
        }
        comp[tid] = (float)CHUNK * b2[cc] + ((a0 + a1) + (a2 + a3));
    }
    __syncthreads();

    {
        float v = comp[tid];
        float s = v, ss = v * v;
        #pragma unroll
        for (int off = 32; off >= 1; off >>= 1) {
            s  += __shfl_xor(s, off, 64);
            ss += __shfl_xor(ss, off, 64);
        }
        if ((tid & 63) == 0) { redA[tid >> 6] = s; redB[tid >> 6] = ss; }
        __syncthreads();
        if (tid == 0) {
            float sa = 0.f, sb2 = 0.f;
            for (int w = 0; w < 16; ++w) { sa += redA[w]; sb2 += redB[w]; }
            const float m = sa * (1.0f / 1024.0f);
            const float var = sb2 * (1.0f / 1024.0f) - m * m;
            mvS[0] = m; mvS[1] = rsqrtf(var + 1e-5f);
        }
        __syncthreads();
        const float m = mvS[0], r = mvS[1];
        comp[tid] = (v - m) * r * lnf_g[tid] + lnf_b[tid];
    }
    __syncthreads();

    {
        const int cc = tid & 63;
        const float v = comp[tid];
        float s = v, ss = v * v;
        #pragma unroll
        for (int off = 32; off >= 1; off >>= 1) {
            s  += __shfl_xor(s, off, 64);
            ss += __shfl_xor(ss, off, 64);
        }
        const float m = s * (1.0f / 64.0f);
        const float var = ss * (1.0f / 64.0f) - m * m;
        const float r = rsqrtf(var + 1e-5f);
        vv[tid] = (v - m) * r * lnd_g[cc] + lnd_b[cc];
    }
    __syncthreads();

    #pragma unroll
    for (int u = 0; u < 2; ++u) {
        const int j4 = (tid + u * 1024) * 4;
        *(float4*)&wbuf[j4] = *(const float4*)(dw1 + j4);
    }
    __syncthreads();
    #pragma unroll
    for (int u = 0; u < 2; ++u) {
        const int j = tid + u * 1024;
        const int l = j >> 7, cc = j & 127;
        const float* vp = vv + l * CDIM;
        float a0 = 0.f, a1 = 0.f, a2 = 0.f, a3 = 0.f;
        for (int k = 0; k < CDIM; k += 4) {
            a0 += vp[k + 0] * wbuf[(k + 0) * H1 + cc];
            a1 += vp[k + 1] * wbuf[(k + 1) * H1 + cc];
            a2 += vp[k + 2] * wbuf[(k + 2) * H1 + cc];
            a3 += vp[k + 3] * wbuf[(k + 3) * H1 + cc];
        }
        hh[j] = gelu_exact(db1[cc] + ((a0 + a1) + (a2 + a3)));
    }
    __syncthreads();

    for (int half = 0; half < 2; ++half) {
        #pragma unroll
        for (int u = 0; u < 4; ++u) {
            const int e = tid + u * 1024;
            const int row = e >> 5, cq = e & 31;
            *(float4*)&wbuf[row * 128 + cq * 4] =
                *(const float4*)(dw2 + (size_t)row * DD + half * 128 + cq * 4);
        }
        __syncthreads();
        #pragma unroll
        for (int u = 0; u < 2; ++u) {
            const int j = tid + u * 1024;
            const int l = j >> 7, cc = j & 127;
            const float* hp = hh + l * H1;
            float a0 = 0.f, a1 = 0.f, a2 = 0.f, a3 = 0.f;
            for (int k = 0; k < H1; k += 4) {
                a0 += hp[k + 0] * wbuf[(k + 0) * 128 + cc];
                a1 += hp[k + 1] * wbuf[(k + 1) * 128 + cc];
                a2 += hp[k + 2] * wbuf[(k + 2) * 128 + cc];
                a3 += hp[k + 3] * wbuf[(k + 3) * 128 + cc];
            }
            decRow[(t * CLEN + l) * DD + half * 128 + cc] =
                db2[half * 128 + cc] + ((a0 + a1) + (a2 + a3));
        }
        __syncthreads();
    }
}

// ---- Kernel 4: out[t,i,:] = decRow[t, idx[t,i]>>11, :] for i<8192 else 0 ----
__global__ __launch_bounds__(256) void k_gather(
    const int* __restrict__ indices, const float* __restrict__ decRow,
    float* __restrict__ out)
{
    const int tid = threadIdx.x;
    const int r = blockIdx.x * 4 + (tid >> 6);
    const int c4 = tid & 63;
    const int t = r / NTOK;
    const int i = r - t * NTOK;
    float4 v = make_float4(0.f, 0.f, 0.f, 0.f);
    if (i < NNODE) {
        const int node = indices[t * NNODE + i];
        const int l = node >> 11;
        v = *(const float4*)(decRow + (t * CLEN + l) * DD + c4 * 4);
    }
    *(float4*)(out + (size_t)r * DD + c4 * 4) = v;
}

extern "C" void kernel_launch(void* const* d_in, const int* in_sizes, int n_in,
                              void* d_out, int out_size, void* d_ws, size_t ws_size,
                              hipStream_t stream)
{
    const float* x       = (const float*)d_in[0];
    const int*   indices = (const int*)d_in[1];
    const float* ln1_g   = (const float*)d_in[2];
    const float* ln1_b   = (const float*)d_in[3];
    const float* w1      = (const float*)d_in[4];
    const float* b1      = (const float*)d_in[5];
    const float* w2      = (const float*)d_in[6];
    const float* b2      = (const float*)d_in[7];
    const float* lnf_g   = (const float*)d_in[8];
    const float* lnf_b   = (const float*)d_in[9];
    const float* lnd_g   = (const float*)d_in[10];
    const float* lnd_b   = (const float*)d_in[11];
    const float* dw1     = (const float*)d_in[12];
    const float* db1     = (const float*)d_in[13];
    const float* dw2     = (const float*)d_in[14];
    const float* db2     = (const float*)d_in[15];
    float* out = (float*)d_out;

    char* ws = (char*)d_ws;
    int*   cnt    = (int*)ws;                            // 1 MiB
    int*   ovfcnt = (int*)(ws + 0x100000);               // 32 B
    // memset region ends at 0x100020
    int*   zc     = (int*)(ws + 0x100040);               // 512 B (plain stores)
    int*   mcntc  = (int*)(ws + 0x100240);               // 512 B (plain stores)
    float* sbuf   = (float*)(ws + 0x100440);             // 64 KiB (plain stores)
    int*   slot0  = (int*)(ws + 0x120000);               // 1 MiB
    int*   slotsx = (int*)(ws + 0x220000);               // 15 MiB -> 0x1120000
    int*   ovf    = (int*)(ws + 0x1120000);              // 256 KiB
    float* decRow = (float*)(ws + 0x1160000);            // 128 KiB
    float* Gv     = (float*)(ws + 0x1180000);            // 512 B
    float* Bv     = (float*)(ws + 0x1180200);            // 512 B
    int*   rowl   = (int*)(ws + 0x1180400);              // 256 KiB
    int*   mlist  = (int*)(ws + 0x1200000);              // 1 MiB
    float* pbuf   = (float*)(ws + 0x1300000);            // 4 MiB
    float* pbuf2  = (float*)(ws + 0x1700000);            // 32 KiB
    float* y      = (float*)(ws + 0x1800000);            // 32 MiB

    hipMemsetAsync(ws, 0, 0x100020, stream);             // cnt + ovfcnt only

    k_prep<<<1, 256, 0, stream>>>(ln1_g, ln1_b, w1, Gv, Bv);
    k_ln_gemm<<<dim3(64, 8), 256, 0, stream>>>(x, indices, ln1_g, w1, Gv, Bv, y,
                                               cnt, slot0, slotsx, ovfcnt, ovf);
    k_classify<<<dim3(16, 8), 256, 0, stream>>>(indices, cnt, rowl, mlist, mcntc, zc);
    k_rowsum<<<dim3(64, 8), 256, 0, stream>>>(y, b1, rowl, pbuf);
    k_multi<<<dim3(4, 16, 8), 256, 0, stream>>>(y, b1, cnt, slot0, slotsx,
                                                ovfcnt, ovf, mlist, mcntc, pbuf2);
    k_sreduce<<<8, 1024, 0, stream>>>(pbuf, pbuf2, sbuf);
    k_decode<<<8, 1024, 0, stream>>>(sbuf, zc, b1, w2, b2, lnf_g, lnf_b,
                                     lnd_g, lnd_b, dw1, db1, dw2, db2, decRow);
    k_gather<<<24576, 256, 0, stream>>>(indices, decRow, out);
}

// Round 7
// 362.560 us; speedup vs baseline: 2.6588x; 1.0946x over previous
//
#include <hip/hip_runtime.h>
#include <math.h>

#define TT 8
#define NTOK 12288
#define DD 256
#define NNODE 8192
#define NNODES 32768
#define CLEN 16
#define CDIM 64
#define CHUNK 2048
#define H1 128

__device__ __forceinline__ float gelu_exact(float v) {
    return 0.5f * v * (1.0f + erff(v * 0.70710678118654752f));
}

// ---- Kernel 1: x @ (g.*w1), LN folded into epilogue; G/B computed in-block;
// rows recorded per node. grid (64, 8), block 512. Tile 128x128, BK=32, 4x8 microtile.
__global__ __launch_bounds__(512, 4) void k_ln_gemm(
    const float* __restrict__ x, const int* __restrict__ indices,
    const float* __restrict__ ln1_g, const float* __restrict__ ln1_b,
    const float* __restrict__ w1, float* __restrict__ y,
    int* __restrict__ cnt, int* __restrict__ slot0, int* __restrict__ slotsx,
    int* __restrict__ ovfcnt, int* __restrict__ ovf)
{
    const int t = blockIdx.y;
    const int rowBase = blockIdx.x * 128;
    const int tid = threadIdx.x;

    __shared__ float As[32 * 132];     // [k][row], stride 132
    __shared__ float Bs[32 * 132];     // [k][col], stride 132
    __shared__ float mS[128], rS[128];
    __shared__ float GS[128], BS[128];
    __shared__ float red[128][4][2];

    const float* xblk = x + ((size_t)t * NTOK + rowBase) * DD;

    // per-node row recording
    if (tid < 128) {
        const int i = rowBase + tid;
        const int node = indices[t * NNODE + i];
        const int g = t * NNODES + node;
        const int pos = atomicAdd(&cnt[g], 1);
        if (pos == 0) slot0[g] = i;
        else if (pos <= 15) slotsx[(size_t)g * 15 + (pos - 1)] = i;
        else {
            const int op = atomicAdd(&ovfcnt[t], 1);
            ovf[t * NNODE + op] = (node << 13) | i;
        }
    }

    // LN stats: 4 threads per row
    {
        const int row = tid >> 2, q = tid & 3;
        const float* xr = xblk + (size_t)row * DD + q * 4;
        float s = 0.f, ss = 0.f;
        #pragma unroll
        for (int u = 0; u < 16; ++u) {
            const float4 v = *(const float4*)(xr + u * 16);
            s  += v.x + v.y + v.z + v.w;
            ss += v.x*v.x + v.y*v.y + v.z*v.z + v.w*v.w;
        }
        red[row][q][0] = s;
        red[row][q][1] = ss;
    }
    __syncthreads();
    if (tid < 128) {
        const float s  = (red[tid][0][0] + red[tid][1][0]) + (red[tid][2][0] + red[tid][3][0]);
        const float ss = (red[tid][0][1] + red[tid][1][1]) + (red[tid][2][1] + red[tid][3][1]);
        const float m = s * (1.0f / 256.0f);
        const float var = ss * (1.0f / 256.0f) - m * m;
        mS[tid] = m;
        rS[tid] = rsqrtf(var + 1e-5f);
    }

    const int ty = tid >> 4;   // 0..31: rows 4ty..4ty+3
    const int tx = tid & 15;   // cols 4tx..+3 and 64+4tx..+3
    float acc[4][8];
    #pragma unroll
    for (int j = 0; j < 4; ++j)
        #pragma unroll
        for (int jj = 0; jj < 8; ++jj) acc[j][jj] = 0.f;

    float4 gp = make_float4(0.f, 0.f, 0.f, 0.f);   // partial G for cols 4*(tid&31)..+3
    float4 bp = make_float4(0.f, 0.f, 0.f, 0.f);   // partial B

    for (int kt = 0; kt < 8; ++kt) {
        __syncthreads();
        // stage A transposed: As[k][row]
        #pragma unroll
        for (int u = 0; u < 2; ++u) {
            const int f = tid + u * 512;
            const int row = f >> 3, c4 = f & 7;
            const float4 v = *(const float4*)(xblk + (size_t)row * DD + kt * 32 + c4 * 4);
            As[(c4 * 4 + 0) * 132 + row] = v.x;
            As[(c4 * 4 + 1) * 132 + row] = v.y;
            As[(c4 * 4 + 2) * 132 + row] = v.z;
            As[(c4 * 4 + 3) * 132 + row] = v.w;
        }
        // stage B = g[k]*w1[k,:]; accumulate G,B partials
        #pragma unroll
        for (int u = 0; u < 2; ++u) {
            const int f = tid + u * 512;
            const int k = f >> 5, c4 = f & 31;   // c4 == tid&31, constant per thread
            const int kg = kt * 32 + k;
            float4 v = *(const float4*)(w1 + (size_t)kg * H1 + c4 * 4);
            const float gk = ln1_g[kg];
            const float bk = ln1_b[kg];
            bp.x += bk * v.x; bp.y += bk * v.y; bp.z += bk * v.z; bp.w += bk * v.w;
            v.x *= gk; v.y *= gk; v.z *= gk; v.w *= gk;
            gp.x += v.x; gp.y += v.y; gp.z += v.z; gp.w += v.w;
            *(float4*)&Bs[132 * k + 4 * c4] = v;
        }
        __syncthreads();
        #pragma unroll
        for (int k = 0; k < 32; ++k) {
            const float4 a  = *(const float4*)&As[k * 132 + 4 * ty];
            const float4 b0 = *(const float4*)&Bs[k * 132 + 4 * tx];
            const float4 b1 = *(const float4*)&Bs[k * 132 + 64 + 4 * tx];
            #pragma unroll
            for (int j = 0; j < 4; ++j) {
                const float aj = (j == 0) ? a.x : (j == 1) ? a.y : (j == 2) ? a.z : a.w;
                acc[j][0] += aj * b0.x; acc[j][1] += aj * b0.y;
                acc[j][2] += aj * b0.z; acc[j][3] += aj * b0.w;
                acc[j][4] += aj * b1.x; acc[j][5] += aj * b1.y;
                acc[j][6] += aj * b1.z; acc[j][7] += aj * b1.w;
            }
        }
    }
    __syncthreads();

    // reduce G/B partials: reuse As (gp) and Bs (bp) as float4[512]
    *(float4*)&As[tid * 4] = gp;
    *(float4*)&Bs[tid * 4] = bp;
    __syncthreads();
    if (tid < 32) {
        float4 G = make_float4(0.f, 0.f, 0.f, 0.f);
        float4 B = make_float4(0.f, 0.f, 0.f, 0.f);
        for (int m = 0; m < 16; ++m) {
            const float4 g4 = *(const float4*)&As[(tid + 32 * m) * 4];
            const float4 b4 = *(const float4*)&Bs[(tid + 32 * m) * 4];
            G.x += g4.x; G.y += g4.y; G.z += g4.z; G.w += g4.w;
            B.x += b4.x; B.y += b4.y; B.z += b4.z; B.w += b4.w;
        }
        *(float4*)&GS[tid * 4] = G;
        *(float4*)&BS[tid * 4] = B;
    }
    __syncthreads();

    // epilogue: y = r*acc - r*m*G + B
    const float4 g0 = *(const float4*)&GS[4 * tx];
    const float4 g1 = *(const float4*)&GS[64 + 4 * tx];
    const float4 bb0 = *(const float4*)&BS[4 * tx];
    const float4 bb1 = *(const float4*)&BS[64 + 4 * tx];
    #pragma unroll
    for (int j = 0; j < 4; ++j) {
        const int r = 4 * ty + j;
        const float m = mS[r], rr = rS[r];
        const float rm = rr * m;
        float* dst = y + (((size_t)t * NNODE + rowBase + r) << 7);
        float4 o0, o1;
        o0.x = rr * acc[j][0] - rm * g0.x + bb0.x;
        o0.y = rr * acc[j][1] - rm * g0.y + bb0.y;
        o0.z = rr * acc[j][2] - rm * g0.z + bb0.z;
        o0.w = rr * acc[j][3] - rm * g0.w + bb0.w;
        o1.x = rr * acc[j][4] - rm * g1.x + bb1.x;
        o1.y = rr * acc[j][5] - rm * g1.y + bb1.y;
        o1.z = rr * acc[j][6] - rm * g1.z + bb1.z;
        o1.w = rr * acc[j][7] - rm * g1.w + bb1.w;
        *(float4*)(dst + 4 * tx) = o0;
        *(float4*)(dst + 64 + 4 * tx) = o1;
    }
}

// ---- Kernel 2a: singleton rows (cnt read inline) -> partials. grid (64, 8), block 256 ----
__global__ __launch_bounds__(256) void k_rowsum(
    const float* __restrict__ y, const float* __restrict__ b1,
    const int* __restrict__ indices, const int* __restrict__ cnt,
    float* __restrict__ pbuf)
{
    const int tid = threadIdx.x;
    const int rb = blockIdx.x * 128;
    const int t = blockIdx.y;
    __shared__ float accS[2][CLEN][H1];
    __shared__ int rl[128];
    for (int e = tid; e < 2 * CLEN * H1; e += 256) ((float*)accS)[e] = 0.f;
    if (tid < 128) {
        const int node = indices[t * NNODE + rb + tid];
        rl[tid] = (cnt[t * NNODES + node] == 1) ? (node >> 11) : -1;
    }
    __syncthreads();
    const int c = tid & 127, h = tid >> 7;
    const float b1c = b1[c];
    const float* ybase = y + (((size_t)t * NNODE + rb) << 7) + c;
    #pragma unroll 4
    for (int r = h; r < 128; r += 2) {
        const float v = ybase[(size_t)r << 7];
        const int l = rl[r];               // wave-uniform
        if (l >= 0) accS[h][l][c] += gelu_exact(v + b1c);
    }
    __syncthreads();
    float* pb = pbuf + ((size_t)t * 64 + blockIdx.x) * (CLEN * H1);
    for (int e = tid; e < CLEN * H1; e += 256) {
        const int l = e >> 7, cc = e & 127;
        pb[e] = accS[0][l][cc] + accS[1][l][cc];
    }
}

// ---- Kernel 2b: scan chunk, find multi nodes + zero count, sum multi nodes. ----
// grid (l 16, t 8), block 256. No global atomics.
__global__ __launch_bounds__(256) void k_multiclass(
    const float* __restrict__ y, const float* __restrict__ b1,
    const int* __restrict__ cnt, const int* __restrict__ slot0,
    const int* __restrict__ slotsx,
    const int* __restrict__ ovfcnt, const int* __restrict__ ovf,
    float* __restrict__ pbuf2, int* __restrict__ zc)
{
    const int l = blockIdx.x, t = blockIdx.y, tid = threadIdx.x;
    __shared__ int mcount;
    __shared__ int mlocal[2048];
    __shared__ int zred[256];
    __shared__ float accS2[2][128];
    if (tid == 0) mcount = 0;
    __syncthreads();
    int z = 0;
    #pragma unroll
    for (int u = 0; u < 8; ++u) {
        const int nid = l * 2048 + u * 256 + tid;
        const int n = cnt[t * NNODES + nid];
        if (n == 0) ++z;
        else if (n >= 2) mlocal[atomicAdd(&mcount, 1)] = nid;   // LDS atomic
    }
    zred[tid] = z;
    __syncthreads();
    for (int st = 128; st > 0; st >>= 1) {
        if (tid < st) zred[tid] += zred[tid + st];
        __syncthreads();
    }
    if (tid == 0) zc[t * CLEN + l] = zred[0];

    const int mc = mcount;
    const int c = tid & 127, h = tid >> 7;
    const float b1c = b1[c];
    const float* ybase = y + (((size_t)t * NNODE) << 7) + c;
    float cs = 0.f;
    for (int j = h; j < mc; j += 2) {
        const int node = mlocal[j];        // wave-uniform
        const int g = t * NNODES + node;
        const int n = cnt[g];
        float acc = b1c + ybase[(size_t)slot0[g] << 7];
        const int m = n < 16 ? n : 16;
        const int* sx = slotsx + (size_t)g * 15;
        for (int q = 0; q < m - 1; ++q)
            acc += ybase[(size_t)sx[q] << 7];
        if (n > 16) {
            int oc = ovfcnt[t]; if (oc > NNODE) oc = NNODE;
            for (int e = 0; e < oc; ++e) {
                const int v = ovf[t * NNODE + e];
                if ((v >> 13) == node) acc += ybase[(size_t)(v & 8191) << 7];
            }
        }
        cs += gelu_exact(acc);
    }
    accS2[h][c] = cs;
    __syncthreads();
    if (tid < 128)
        pbuf2[(t * CLEN + l) * 128 + c] = accS2[0][c] + accS2[1][c];
}

// ---- Kernel 3: decode (partials reduced inline). grid 8, block 1024. ----
__global__ __launch_bounds__(1024) void k_decode(
    const float* __restrict__ pbuf, const float* __restrict__ pbuf2,
    const int* __restrict__ zc, const float* __restrict__ b1,
    const float* __restrict__ w2, const float* __restrict__ b2,
    const float* __restrict__ lnf_g, const float* __restrict__ lnf_b,
    const float* __restrict__ lnd_g, const float* __restrict__ lnd_b,
    const float* __restrict__ dw1, const float* __restrict__ db1,
    const float* __restrict__ dw2, const float* __restrict__ db2,
    float* __restrict__ decRow)
{
    const int t = blockIdx.x, tid = threadIdx.x;
    __shared__ float wbuf[16384];
    __shared__ float sb[CLEN * H1];
    __shared__ float comp[1024];
    __shared__ float vv[1024];
    __shared__ float hh[CLEN * H1];
    __shared__ float redA[16], redB[16];
    __shared__ float mvS[2];

    // sb = sum of 64 singleton partials + multi partial + zero-count analytic term
    #pragma unroll
    for (int u = 0; u < 2; ++u) {
        const int e = tid + u * 1024;
        float s = 0.f;
        const float* pp = pbuf + (size_t)t * 64 * (CLEN * H1) + e;
        #pragma unroll 8
        for (int p = 0; p < 64; ++p) s += pp[(size_t)p * (CLEN * H1)];
        const int l = e >> 7, k = e & 127;
        s += pbuf2[t * (CLEN * H1) + e];
        sb[e] = s + (float)zc[t * CLEN + l] * gelu_exact(b1[k]);
    }
    #pragma unroll
    for (int u = 0; u < 2; ++u) {
        const int j4 = (tid + u * 1024) * 4;
        *(float4*)&wbuf[j4] = *(const float4*)(w2 + j4);
    }
    __syncthreads();

    {
        const int l = tid >> 6, cc = tid & 63;
        const float* sp = sb + l * H1;
        float a0 = 0.f, a1 = 0.f, a2 = 0.f, a3 = 0.f;
        for (int k = 0; k < H1; k += 4) {
            a0 += sp[k + 0] * wbuf[(k + 0) * CDIM + cc];
            a1 += sp[k + 1] * wbuf[(k + 1) * CDIM + cc];
            a2 += sp[k + 2] * wbuf[(k + 2) * CDIM + cc];
            a3 += sp[k + 3] * wbuf[(k + 3) * CDIM + cc];
        }
        comp[tid] = (float)CHUNK * b2[cc] + ((a0 + a1) + (a2 + a3));
    }
    __syncthreads();

    {
        float v = comp[tid];
        float s = v, ss = v * v;
        #pragma unroll
        for (int off = 32; off >= 1; off >>= 1) {
            s  += __shfl_xor(s, off, 64);
            ss += __shfl_xor(ss, off, 64);
        }
        if ((tid & 63) == 0) { redA[tid >> 6] = s; redB[tid >> 6] = ss; }
        __syncthreads();
        if (tid == 0) {
            float sa = 0.f, sb2 = 0.f;
            for (int w = 0; w < 16; ++w) { sa += redA[w]; sb2 += redB[w]; }
            const float m = sa * (1.0f / 1024.0f);
            const float var = sb2 * (1.0f / 1024.0f) - m * m;
            mvS[0] = m; mvS[1] = rsqrtf(var + 1e-5f);
        }
        __syncthreads();
        const float m = mvS[0], r = mvS[1];
        comp[tid] = (v - m) * r * lnf_g[tid] + lnf_b[tid];
    }
    __syncthreads();

    {
        const int cc = tid & 63;
        const float v = comp[tid];
        float s = v, ss = v * v;
        #pragma unroll
        for (int off = 32; off >= 1; off >>= 1) {
            s  += __shfl_xor(s, off, 64);
            ss += __shfl_xor(ss, off, 64);
        }
        const float m = s * (1.0f / 64.0f);
        const float var = ss * (1.0f / 64.0f) - m * m;
        const float r = rsqrtf(var + 1e-5f);
        vv[tid] = (v - m) * r * lnd_g[cc] + lnd_b[cc];
    }
    __syncthreads();

    #pragma unroll
    for (int u = 0; u < 2; ++u) {
        const int j4 = (tid + u * 1024) * 4;
        *(float4*)&wbuf[j4] = *(const float4*)(dw1 + j4);
    }
    __syncthreads();
    #pragma unroll
    for (int u = 0; u < 2; ++u) {
        const int j = tid + u * 1024;
        const int l = j >> 7, cc = j & 127;
        const float* vp = vv + l * CDIM;
        float a0 = 0.f, a1 = 0.f, a2 = 0.f, a3 = 0.f;
        for (int k = 0; k < CDIM; k += 4) {
            a0 += vp[k + 0] * wbuf[(k + 0) * H1 + cc];
            a1 += vp[k + 1] * wbuf[(k + 1) * H1 + cc];
            a2 += vp[k + 2] * wbuf[(k + 2) * H1 + cc];
            a3 += vp[k + 3] * wbuf[(k + 3) * H1 + cc];
        }
        hh[j] = gelu_exact(db1[cc] + ((a0 + a1) + (a2 + a3)));
    }
    __syncthreads();

    for (int half = 0; half < 2; ++half) {
        #pragma unroll
        for (int u = 0; u < 4; ++u) {
            const int e = tid + u * 1024;
            const int row = e >> 5, cq = e & 31;
            *(float4*)&wbuf[row * 128 + cq * 4] =
                *(const float4*)(dw2 + (size_t)row * DD + half * 128 + cq * 4);
        }
        __syncthreads();
        #pragma unroll
        for (int u = 0; u < 2; ++u) {
            const int j = tid + u * 1024;
            const int l = j >> 7, cc = j & 127;
            const float* hp = hh + l * H1;
            float a0 = 0.f, a1 = 0.f, a2 = 0.f, a3 = 0.f;
            for (int k = 0; k < H1; k += 4) {
                a0 += hp[k + 0] * wbuf[(k + 0) * 128 + cc];
                a1 += hp[k + 1] * wbuf[(k + 1) * 128 + cc];
                a2 += hp[k + 2] * wbuf[(k + 2) * 128 + cc];
                a3 += hp[k + 3] * wbuf[(k + 3) * 128 + cc];
            }
            decRow[(t * CLEN + l) * DD + half * 128 + cc] =
                db2[half * 128 + cc] + ((a0 + a1) + (a2 + a3));
        }
        __syncthreads();
    }
}

// ---- Kernel 4: out[t,i,:] = decRow[t, idx[t,i]>>11, :] for i<8192 else 0 ----
__global__ __launch_bounds__(256) void k_gather(
    const int* __restrict__ indices, const float* __restrict__ decRow,
    float* __restrict__ out)
{
    const int tid = threadIdx.x;
    const int r = blockIdx.x * 4 + (tid >> 6);
    const int c4 = tid & 63;
    const int t = r / NTOK;
    const int i = r - t * NTOK;
    float4 v = make_float4(0.f, 0.f, 0.f, 0.f);
    if (i < NNODE) {
        const int node = indices[t * NNODE + i];
        const int l = node >> 11;
        v = *(const float4*)(decRow + (t * CLEN + l) * DD + c4 * 4);
    }
    *(float4*)(out + (size_t)r * DD + c4 * 4) = v;
}

extern "C" void kernel_launch(void* const* d_in, const int* in_sizes, int n_in,
                              void* d_out, int out_size, void* d_ws, size_t ws_size,
                              hipStream_t stream)
{
    const float* x       = (const float*)d_in[0];
    const int*   indices = (const int*)d_in[1];
    const float* ln1_g   = (const float*)d_in[2];
    const float* ln1_b   = (const float*)d_in[3];
    const float* w1      = (const float*)d_in[4];
    const float* b1      = (const float*)d_in[5];
    const float* w2      = (const float*)d_in[6];
    const float* b2      = (const float*)d_in[7];
    const float* lnf_g   = (const float*)d_in[8];
    const float* lnf_b   = (const float*)d_in[9];
    const float* lnd_g   = (const float*)d_in[10];
    const float* lnd_b   = (const float*)d_in[11];
    const float* dw1     = (const float*)d_in[12];
    const float* db1     = (const float*)d_in[13];
    const float* dw2     = (const float*)d_in[14];
    const float* db2     = (const float*)d_in[15];
    float* out = (float*)d_out;

    char* ws = (char*)d_ws;
    int*   cnt    = (int*)ws;                            // 1 MiB
    int*   ovfcnt = (int*)(ws + 0x100000);               // 32 B
    // memset ends at 0x100020
    int*   zc     = (int*)(ws + 0x100040);               // 512 B (plain stores)
    int*   slot0  = (int*)(ws + 0x120000);               // 1 MiB
    int*   slotsx = (int*)(ws + 0x220000);               // 15 MiB -> 0x1120000
    int*   ovf    = (int*)(ws + 0x1120000);              // 256 KiB
    float* decRow = (float*)(ws + 0x1160000);            // 128 KiB
    float* pbuf   = (float*)(ws + 0x1300000);            // 4 MiB  (plain stores)
    float* pbuf2  = (float*)(ws + 0x1700000);            // 64 KiB (plain stores)
    float* y      = (float*)(ws + 0x1800000);            // 32 MiB

    hipMemsetAsync(ws, 0, 0x100020, stream);             // cnt + ovfcnt only

    k_ln_gemm<<<dim3(64, 8), 512, 0, stream>>>(x, indices, ln1_g, ln1_b, w1, y,
                                               cnt, slot0, slotsx, ovfcnt, ovf);
    k_rowsum<<<dim3(64, 8), 256, 0, stream>>>(y, b1, indices, cnt, pbuf);
    k_multiclass<<<dim3(16, 8), 256, 0, stream>>>(y, b1, cnt, slot0, slotsx,
                                                  ovfcnt, ovf, pbuf2, zc);
    k_decode<<<8, 1024, 0, stream>>>(pbuf, pbuf2, zc, b1, w2, b2, lnf_g, lnf_b,
                                     lnd_g, lnd_b, dw1, db1, dw2, db2, decRow);
    k_gather<<<24576, 256, 0, stream>>>(indices, decRow, out);
}